// Round 5
// baseline (166.411 us; speedup 1.0000x reference)
//
#include <hip/hip_runtime.h>
#include <hip/hip_bf16.h>

#define B_  16384
#define I_  512
#define H1_ 256
#define H2_ 128
#define E_  8
#define T_  2

typedef __attribute__((ext_vector_type(8))) short short8;
typedef __attribute__((ext_vector_type(4))) float float4_t;

__device__ inline unsigned short f2bf(float f) {
    union { float f; unsigned u; } v; v.f = f;
    unsigned r = v.u + 0x7FFFu + ((v.u >> 16) & 1u);
    return (unsigned short)(r >> 16);
}

// async global->LDS, 16B per lane. LDS dest = wave-uniform base + lane*16.
__device__ inline void async_copy16(const unsigned short* g, unsigned short* l) {
    __builtin_amdgcn_global_load_lds(
        (const __attribute__((address_space(1))) void*)g,
        (__attribute__((address_space(3))) void*)l,
        16, 0, 0);
}

#define BAR()  asm volatile("s_barrier" ::: "memory")
#define LGKM() do { asm volatile("s_waitcnt lgkmcnt(0)" ::: "memory"); \
                    __builtin_amdgcn_sched_barrier(0); } while (0)

// ================= prep + gates megakernel (one dispatch) =================
// UNCHANGED (verified): x->bf16 (xb), W1^T (w1t), W2^T (w2t), gate softmax.
__global__ void prep_gates_kernel(const float* __restrict__ x,
                                  unsigned short* __restrict__ xb,
                                  const float* __restrict__ W1,
                                  unsigned short* __restrict__ w1t,
                                  const float* __restrict__ W2,
                                  unsigned short* __restrict__ w2t,
                                  const float* __restrict__ Wg,
                                  const float* __restrict__ bg,
                                  float* __restrict__ gates) {
    __shared__ __align__(16) char smem[16 * 520 * 2 + 4 * 16 * 16 * 4];  // 20.6 KB
    int bid = blockIdx.x;
    int t = threadIdx.x;

    if (bid < 1024) {
        unsigned short* wgtL = (unsigned short*)smem;          // [16][520] padded
        float (*red)[16][16] = (float (*)[16][16])(smem + 16 * 520 * 2);
#pragma unroll
        for (int j = 0; j < 32; ++j) {
            int idx = j * 256 + t;               // 0..8191
            int e = idx & 7, i = (idx >> 3) & 511, task = idx >> 12;
            wgtL[(task * 8 + e) * 520 + i] = f2bf(Wg[idx]);
        }
        __syncthreads();

        int w = t >> 6, lane = t & 63;
        int col = lane & 15, quad = lane >> 4;
        int b0 = bid * 16;
        int k0 = w * 128;
        const float* xr = x + (size_t)(b0 + col) * I_ + k0 + quad * 8;
        unsigned short* xw = xb + (size_t)(b0 + col) * I_ + k0 + quad * 8;
        const unsigned short* bL = &wgtL[col * 520 + k0 + quad * 8];
        float4_t acc = {0.f, 0.f, 0.f, 0.f};
#pragma unroll
        for (int ks = 0; ks < 128; ks += 32) {
            float4_t xa = *(const float4_t*)(xr + ks);
            float4_t xc = *(const float4_t*)(xr + ks + 4);
            short8 a;
            a[0] = (short)f2bf(xa[0]); a[1] = (short)f2bf(xa[1]);
            a[2] = (short)f2bf(xa[2]); a[3] = (short)f2bf(xa[3]);
            a[4] = (short)f2bf(xc[0]); a[5] = (short)f2bf(xc[1]);
            a[6] = (short)f2bf(xc[2]); a[7] = (short)f2bf(xc[3]);
            *(short8*)(xw + ks) = a;
            short8 b = *(const short8*)(bL + ks);
            acc = __builtin_amdgcn_mfma_f32_16x16x32_bf16(a, b, acc, 0, 0, 0);
        }
#pragma unroll
        for (int p = 0; p < 4; ++p)
            red[w][quad * 4 + p][col] = acc[p];
        __syncthreads();
        int r = t >> 4, te = t & 15;
        float v = red[0][r][te] + red[1][r][te] + red[2][r][te] + red[3][r][te] + bg[te];
        float m = v;
        m = fmaxf(m, __shfl_xor(m, 1));
        m = fmaxf(m, __shfl_xor(m, 2));
        m = fmaxf(m, __shfl_xor(m, 4));
        float ev = __expf(v - m);
        float s = ev;
        s += __shfl_xor(s, 1);
        s += __shfl_xor(s, 2);
        s += __shfl_xor(s, 4);
        gates[(size_t)te * B_ + b0 + r] = ev / s;
    } else {
        float (*tile)[33] = (float (*)[33])smem;
        const float* in; unsigned short* outp; int R, C, e, r0, c0;
        if (bid < 2048) {
            int tl = bid - 1024;               // 8 e x 16 rblk x 8 cblk
            e = tl >> 7; int rem = tl & 127;
            R = I_; C = H1_;
            r0 = (rem >> 3) * 32; c0 = (rem & 7) * 32;
            in = W1; outp = w1t;
        } else {
            int tl = bid - 2048;               // 8 e x 8 rblk x 4 cblk
            e = tl >> 5; int rem = tl & 31;
            R = H1_; C = H2_;
            r0 = (rem >> 2) * 32; c0 = (rem & 3) * 32;
            in = W2; outp = w2t;
        }
        const float* inp = in + (size_t)e * R * C;
        unsigned short* op = outp + (size_t)e * R * C;
        int tx = t & 31, ty = t >> 5;          // (32, 8)
#pragma unroll
        for (int j = 0; j < 32; j += 8)
            tile[ty + j][tx] = inp[(size_t)(r0 + ty + j) * C + c0 + tx];
        __syncthreads();
#pragma unroll
        for (int j = 0; j < 32; j += 8)
            op[(size_t)(c0 + ty + j) * R + r0 + tx] = f2bf(tile[tx][ty + j]);
    }
}

// ================= layer-1 GEMM: 256x256 tile, m201-style 8-phase region-recycled =================
// h[e] = relu(xb * w1t[e]^T + b1[e]) bf16. M=B, N=H1=256, K=512 (8 K-tiles, 2/iter).
// 8 waves (2M x 4N), per-wave out 128x64. LDS 128 KB: buf0=even K-tile, buf1=odd,
// region-packed rows (bit-swap) so each quadrant-phase reads one contiguous 16 KB
// region that DIES at that phase's end barrier. Stage schedule (region <- next tile):
//   P1: B1.n0  P2: A0.m0  P4: A0.m1+B0.n1 [vmcnt6]  P5: B0.n0
//   P6: A1.m0  P8: A1.m1+B1.n1 [vmcnt6]
// Every staged target is dead >=1 barrier before issue; vmcnt(6) at P4/P8 covers
// all reads (<=3 regions = 6 loads in flight). Tail iter uses vmcnt(0).
__global__ __launch_bounds__(512, 2)
void l1_gemm_kernel(const unsigned short* __restrict__ xb,
                    const unsigned short* __restrict__ w1t,
                    const float* __restrict__ b1,
                    unsigned short* __restrict__ h) {
    __shared__ __align__(16) unsigned short smem[65536];   // 128 KB

    // XCD-bijective swizzle (512 = 8*64)
    int bid = blockIdx.x;
    int wg = (bid & 7) * 64 + (bid >> 3);
    int m0 = (wg >> 3) * 256;
    int e  = wg & 7;

    int t = threadIdx.x, w = t >> 6, lane = t & 63;
    int col = lane & 15, quad = lane >> 4;
    int wm = (w & 1) * 128;
    int wn = (w >> 1) * 64;

    int cswT = ((t & 7) ^ ((t >> 3) & 7)) * 8;     // pre-swizzled source chunk (key = lds_row&7)

    unsigned short* As = smem;                // [2 tiles][256 lds-rows][64]
    unsigned short* Bs = smem + 32768;

    float4_t acc[8][4];
#pragma unroll
    for (int mf = 0; mf < 8; ++mf)
#pragma unroll
        for (int nf = 0; nf < 4; ++nf)
            acc[mf][nf] = (float4_t){0.f, 0.f, 0.f, 0.f};

    // region stagers: 2 rounds x (512 thr x 16 B) = 16 KB region (128 lds-rows)
    // A lds_row = bitswap6,7(m)  (involution);  B lds_row = b5<<7|b7<<6|b6<<5|low5
    auto stageA = [&](int kt, int mq, int bsel) {
#pragma unroll
        for (int hh = 0; hh < 2; ++hh) {
            int lr = mq * 128 + hh * 64 + (t >> 3);
            int m  = ((lr >> 6) & 1) * 128 + ((lr >> 7) & 1) * 64 + (lr & 63);
            async_copy16(xb + (size_t)(m0 + m) * I_ + kt * 64 + cswT,
                         As + bsel * 16384 + lr * 64 + (t & 7) * 8);
        }
    };
    auto stageB = [&](int kt, int nq, int bsel) {
#pragma unroll
        for (int hh = 0; hh < 2; ++hh) {
            int lr = nq * 128 + hh * 64 + (t >> 3);
            int n  = ((lr >> 6) & 1) * 128 + ((lr >> 5) & 1) * 64 + ((lr >> 7) & 1) * 32 + (lr & 31);
            async_copy16(w1t + ((size_t)e * H1_ + n) * I_ + kt * 64 + cswT,
                         Bs + bsel * 16384 + lr * 64 + (t & 7) * 8);
        }
    };
    auto dsA = [&](int bsel, int mq, short8 af[4][2]) {
#pragma unroll
        for (int m2 = 0; m2 < 4; ++m2) {
            int r  = wm + (mq * 4 + m2) * 16 + col;
            int lr = ((r >> 6) & 1) * 128 + ((r >> 7) & 1) * 64 + (r & 63);
#pragma unroll
            for (int kq = 0; kq < 2; ++kq) {
                int q = kq * 4 + quad;
                af[m2][kq] = *(const short8*)&As[bsel * 16384 + lr * 64 + ((q ^ (r & 7)) << 3)];
            }
        }
    };
    auto dsB = [&](int bsel, int nq, short8 bf[2][2]) {
#pragma unroll
        for (int n2 = 0; n2 < 2; ++n2) {
            int n  = wn + (nq * 2 + n2) * 16 + col;
            int lr = ((n >> 5) & 1) * 128 + ((n >> 7) & 1) * 64 + ((n >> 6) & 1) * 32 + (n & 31);
#pragma unroll
            for (int kq = 0; kq < 2; ++kq) {
                int q = kq * 4 + quad;
                bf[n2][kq] = *(const short8*)&Bs[bsel * 16384 + lr * 64 + ((q ^ (n & 7)) << 3)];
            }
        }
    };
    auto mfmaQ = [&](short8 af[4][2], short8 bf[2][2], int mq, int nq) {
        __builtin_amdgcn_s_setprio(1);
#pragma unroll
        for (int m2 = 0; m2 < 4; ++m2)
#pragma unroll
            for (int n2 = 0; n2 < 2; ++n2)
#pragma unroll
                for (int kq = 0; kq < 2; ++kq)
                    acc[mq * 4 + m2][nq * 2 + n2] = __builtin_amdgcn_mfma_f32_16x16x32_bf16(
                        af[m2][kq], bf[n2][kq], acc[mq * 4 + m2][nq * 2 + n2], 0, 0, 0);
        __builtin_amdgcn_s_setprio(0);
    };

    // prologue: tile0 complete (8 rounds) + tile1 A.m0/A.m1/B.n1 (6 rounds)
    stageA(0, 0, 0); stageA(0, 1, 0); stageB(0, 0, 0); stageB(0, 1, 0);
    stageA(1, 0, 1); stageA(1, 1, 1); stageB(1, 1, 1);
    asm volatile("s_waitcnt vmcnt(6)" ::: "memory");   // oldest 8 (tile0) landed
    BAR();

#pragma unroll 1
    for (int j = 0; j < 4; ++j) {
        short8 af[4][2], bf[2][2];
        const int u = 2 * j, v = 2 * j + 1;
        // ---- P1: Q(m0,n0) of tile u; stage B1.n0 <- tile v ----
        dsA(0, 0, af); dsB(0, 0, bf);
        stageB(v, 0, 1);
        BAR(); LGKM(); mfmaQ(af, bf, 0, 0); BAR();
        // ---- P2: Q(m0,n1); stage A0.m0 <- u+2 ----
        dsB(0, 1, bf);
        if (j < 3) stageA(u + 2, 0, 0);
        BAR(); LGKM(); mfmaQ(af, bf, 0, 1); BAR();
        // ---- P3: Q(m1,n1) ----
        dsA(0, 1, af);
        BAR(); LGKM(); mfmaQ(af, bf, 1, 1); BAR();
        // ---- P4: Q(m1,n0); stage A0.m1 + B0.n1 <- u+2; vmcnt ----
        dsB(0, 0, bf);
        if (j < 3) {
            stageA(u + 2, 1, 0); stageB(u + 2, 1, 0);
            asm volatile("s_waitcnt vmcnt(6)" ::: "memory");
        } else {
            asm volatile("s_waitcnt vmcnt(0)" ::: "memory");
        }
        BAR(); LGKM(); mfmaQ(af, bf, 1, 0); BAR();
        // ---- P5: Q(m0,n0) of tile v; stage B0.n0 <- u+2 ----
        dsA(1, 0, af); dsB(1, 0, bf);
        if (j < 3) stageB(u + 2, 0, 0);
        BAR(); LGKM(); mfmaQ(af, bf, 0, 0); BAR();
        // ---- P6: Q(m0,n1); stage A1.m0 <- v+2 ----
        dsB(1, 1, bf);
        if (j < 3) stageA(v + 2, 0, 1);
        BAR(); LGKM(); mfmaQ(af, bf, 0, 1); BAR();
        // ---- P7: Q(m1,n1) ----
        dsA(1, 1, af);
        BAR(); LGKM(); mfmaQ(af, bf, 1, 1); BAR();
        // ---- P8: Q(m1,n0); stage A1.m1 + B1.n1 <- v+2; vmcnt ----
        dsB(1, 0, bf);
        if (j < 3) {
            stageA(v + 2, 1, 1); stageB(v + 2, 1, 1);
            asm volatile("s_waitcnt vmcnt(6)" ::: "memory");
        } else {
            asm volatile("s_waitcnt vmcnt(0)" ::: "memory");
        }
        BAR(); LGKM(); mfmaQ(af, bf, 1, 0); BAR();
    }

    // ---- epilogue: bias + relu -> bf16, LDS-restaged coalesced stores (as r4) ----
    unsigned short* Ct = smem;                 // [128][stride 264] per half
    const float* bE = b1 + e * H1_;
#pragma unroll
    for (int half = 0; half < 2; ++half) {
        if ((w & 1) == half) {
#pragma unroll
            for (int mf = 0; mf < 8; ++mf) {
#pragma unroll
                for (int nf = 0; nf < 4; ++nf) {
                    int n = wn + nf * 16 + col;
                    float bv = bE[n];
#pragma unroll
                    for (int p2 = 0; p2 < 4; ++p2) {
                        float v = acc[mf][nf][p2] + bv;
                        v = v > 0.f ? v : 0.f;
                        Ct[(mf * 16 + quad * 4 + p2) * 264 + n] = f2bf(v);
                    }
                }
            }
        }
        __syncthreads();
        unsigned short* hrow = h + ((size_t)e * B_ + m0 + half * 128) * H1_;
#pragma unroll
        for (int j = 0; j < 8; ++j) {
            int idx = j * 512 + t;
            int row = idx >> 5, cc = idx & 31;
            short8 vv = *(const short8*)&Ct[row * 264 + cc * 8];
            *(short8*)&hrow[(size_t)row * H1_ + cc * 8] = vv;
        }
        __syncthreads();
    }
}

// ---------------- fused layer2 + gated combine: ring-3, depth-1 prefetch ----------------
// UNCHANGED (verified r4). 64 rows x full H2 per block, grid 256, 76 KB -> 2 blocks/CU.
__global__ __launch_bounds__(512, 4)
void fused_l2_combine_kernel(const unsigned short* __restrict__ h,
                             const unsigned short* __restrict__ w2t,
                             const float* __restrict__ b2,
                             const float* __restrict__ gates,
                             float* __restrict__ out) {
    __shared__ __align__(16) unsigned short ring[36864];   // 72 KB: A[3][4096] | B[3][8192]
    __shared__ float gL[16][64];                           //  4 KB

    unsigned short* Aslot = ring;
    unsigned short* Bslot = ring + 12288;

    int b0 = blockIdx.x * 64;
    int t = threadIdx.x, w = t >> 6, lane = t & 63;
    int col = lane & 15, quad = lane >> 4;
    int wm = (w & 1) * 32, wn = (w >> 1) * 32;

    if (t < 256) {
        int te = t >> 4, r4 = (t & 15) * 4;
        *(float4_t*)&gL[te][r4] = *(const float4_t*)&gates[(size_t)te * B_ + b0 + r4];
    }

    int rowA = t >> 3;
    int csw  = ((t & 7) ^ (rowA & 7)) * 8;
    int ldsw = w * 512;

    float4_t tw0[2][2], tw1[2][2];
#pragma unroll
    for (int mi = 0; mi < 2; ++mi)
#pragma unroll
        for (int ni = 0; ni < 2; ++ni) {
            tw0[mi][ni] = (float4_t){0.f, 0.f, 0.f, 0.f};
            tw1[mi][ni] = (float4_t){0.f, 0.f, 0.f, 0.f};
        }

    auto stage = [&](int cid, int slot) {
        int ee = cid >> 2, kc = cid & 3;
        const unsigned short* hE = h + ((size_t)ee * B_ + b0 + rowA) * H1_ + kc * 64 + csw;
        async_copy16(hE, Aslot + slot * 4096 + ldsw);
        const unsigned short* wE = w2t + ((size_t)ee * H2_ + rowA) * H1_ + kc * 64 + csw;
        async_copy16(wE, Bslot + slot * 8192 + ldsw);
        async_copy16(wE + (size_t)64 * H1_, Bslot + slot * 8192 + 4096 + ldsw);
    };

    stage(0, 0);

    float4_t acc[2][2];
    int rd = 0, wr = 1;
#pragma unroll 1
    for (int cid = 0; cid < 32; ++cid) {
        if (cid < 31) {
            stage(cid + 1, wr);
            asm volatile("s_waitcnt vmcnt(3)" ::: "memory");
        } else {
            asm volatile("s_waitcnt vmcnt(0)" ::: "memory");
        }
        asm volatile("s_barrier" ::: "memory");

        if ((cid & 3) == 0) {
#pragma unroll
            for (int mi = 0; mi < 2; ++mi)
#pragma unroll
                for (int ni = 0; ni < 2; ++ni)
                    acc[mi][ni] = (float4_t){0.f, 0.f, 0.f, 0.f};
        }
        const unsigned short* Ac = Aslot + rd * 4096;
        const unsigned short* Bc = Bslot + rd * 8192;
#pragma unroll
        for (int kq = 0; kq < 2; ++kq) {
            int q = kq * 4 + quad;
            short8 af[2], bfv[2];
#pragma unroll
            for (int mi = 0; mi < 2; ++mi) {
                int r = wm + mi * 16 + col;
                af[mi] = *(const short8*)&Ac[r * 64 + ((q ^ (r & 7)) << 3)];
            }
#pragma unroll
            for (int ni = 0; ni < 2; ++ni) {
                int n = wn + ni * 16 + col;
                bfv[ni] = *(const short8*)&Bc[n * 64 + ((q ^ (n & 7)) << 3)];
            }
            __builtin_amdgcn_s_setprio(1);
#pragma unroll
            for (int mi = 0; mi < 2; ++mi)
#pragma unroll
                for (int ni = 0; ni < 2; ++ni)
                    acc[mi][ni] = __builtin_amdgcn_mfma_f32_16x16x32_bf16(
                        af[mi], bfv[ni], acc[mi][ni], 0, 0, 0);
            __builtin_amdgcn_s_setprio(0);
        }

        if ((cid & 3) == 3) {
            int ee = cid >> 2;
#pragma unroll
            for (int ni = 0; ni < 2; ++ni) {
                float bv = b2[ee * H2_ + wn + ni * 16 + col];
#pragma unroll
                for (int mi = 0; mi < 2; ++mi) {
#pragma unroll
                    for (int p = 0; p < 4; ++p) {
                        int rloc = wm + mi * 16 + quad * 4 + p;
                        float v = acc[mi][ni][p] + bv;
                        v = v > 0.f ? v : 0.f;
                        tw0[mi][ni][p] += gL[ee][rloc] * v;
                        tw1[mi][ni][p] += gL[8 + ee][rloc] * v;
                    }
                }
            }
        }
        rd = (rd == 2) ? 0 : rd + 1;
        wr = (wr == 2) ? 0 : wr + 1;
    }

#pragma unroll
    for (int mi = 0; mi < 2; ++mi) {
#pragma unroll
        for (int ni = 0; ni < 2; ++ni) {
            int n = wn + ni * 16 + col;
#pragma unroll
            for (int p = 0; p < 4; ++p) {
                int r = b0 + wm + mi * 16 + quad * 4 + p;
                out[(size_t)r * H2_ + n] = tw0[mi][ni][p];
                out[(size_t)B_ * H2_ + (size_t)r * H2_ + n] = tw1[mi][ni][p];
            }
        }
    }
}

extern "C" void kernel_launch(void* const* d_in, const int* in_sizes, int n_in,
                              void* d_out, int out_size, void* d_ws, size_t ws_size,
                              hipStream_t stream) {
    const float* x  = (const float*)d_in[0];
    const float* W1 = (const float*)d_in[1];
    const float* b1 = (const float*)d_in[2];
    const float* W2 = (const float*)d_in[3];
    const float* b2 = (const float*)d_in[4];
    const float* Wg = (const float*)d_in[5];
    const float* bg = (const float*)d_in[6];
    float* out = (float*)d_out;

    char* ws = (char*)d_ws;
    unsigned short* xb    = (unsigned short*)(ws);                // 16,777,216 B
    unsigned short* w1t   = (unsigned short*)(ws + 16777216);     //  2,097,152 B
    unsigned short* w2t   = (unsigned short*)(ws + 18874368);     //    524,288 B
    float*          gates = (float*)(ws + 19398656);              //  1,048,576 B  [16][B]
    unsigned short* h     = (unsigned short*)(ws + 20447232);     // 67,108,864 B
    // total: 87,556,096 B

    prep_gates_kernel<<<dim3(2304), 256, 0, stream>>>(x, xb, W1, w1t, W2, w2t, Wg, bg, gates);

    l1_gemm_kernel<<<dim3(512), 512, 0, stream>>>(xb, w1t, b1, h);

    fused_l2_combine_kernel<<<dim3(B_ / 64), 512, 0, stream>>>(h, w2t, b2, gates, out);
}